// Round 2
// baseline (2515.828 us; speedup 1.0000x reference)
//
#include <hip/hip_runtime.h>

typedef __attribute__((ext_vector_type(8))) short bfv8;
typedef __attribute__((ext_vector_type(4))) float f32x4;

__device__ __forceinline__ float bf2f(unsigned short u) {
  union { unsigned int i; float f; } c; c.i = ((unsigned int)u) << 16; return c.f;
}
__device__ __forceinline__ unsigned short f2bf(float f) {
  union { float f; unsigned int i; } c; c.f = f;
  unsigned int r = c.i + 0x7FFFu + ((c.i >> 16) & 1u);
  return (unsigned short)(r >> 16);
}
__device__ __forceinline__ float gelu_(float x) {
  return 0.5f * x * (1.0f + erff(x * 0.70710678118654752f));
}
__device__ __forceinline__ int div9(int col) {
  return (int)(__umulhi((unsigned)col, 954437177u) >> 1);
}

// ---------------- weight prep: fp32 -> bf16 (+ conv weight transpose) ----------
__global__ void k_prep(const float* c1w, const float* c2w, const float* c3w,
                       unsigned short* W1b, unsigned short* W2t, unsigned short* W3b) {
  int i = blockIdx.x * 256 + threadIdx.x;
  if (i < 262144) { W1b[i] = f2bf(c1w[i]); return; }
  i -= 262144;
  if (i < 655360) {   // W2t[l][t][o][ii] = c2w[l][o][ii][t]
    int ii = i & 255, o = (i >> 8) & 255, rest = i >> 16;
    int t = rest % 5, l = rest / 5;
    W2t[i] = f2bf(c2w[(((l * 256 + o) << 8) + ii) * 5 + t]);
    return;
  }
  i -= 655360;
  if (i < 262144) { W3b[i] = f2bf(c3w[i]); }
}

// ---------------- build X0 for one chunk: [c][nl*9+k] bf16 --------------------
__global__ void k_x0(const int* x, const float* emb, unsigned short* X,
                     int n0, int ncBits, int ncMask, int nkc) {
  int idx = blockIdx.x * 256 + threadIdx.x;
  int nl = idx & ncMask, c = idx >> ncBits;
  int gn = n0 + nl;
  int b = gn >> 11, w = gn & 2047;
  unsigned short* dst = X + (size_t)c * nkc + nl * 9;
  for (int k = 0; k < 9; k++) {
    int t = w + k; if (t > 2047) t = 2047;      // clamp for padded windows
    int tok = x[(b << 11) + t];
    dst[k] = f2bf(emb[tok * 512 + c]);
  }
}

// --------- fused per-(c,n) instance-norm (+affine) + gelu, any #channels ------
__global__ void k_ng(const unsigned short* H, const float* g, const float* bb,
                     unsigned short* T, int ncBits, int ncMask, int nkc) {
  int idx = blockIdx.x * 256 + threadIdx.x;
  int nl = idx & ncMask, c = idx >> ncBits;
  const unsigned short* p = H + (size_t)c * nkc + nl * 9;
  unsigned short* d = T + (size_t)c * nkc + nl * 9;
  float v[9], s = 0.f;
  for (int k = 0; k < 9; k++) { v[k] = bf2f(p[k]); s += v[k]; }
  float m = s * (1.0f / 9.0f), q = 0.f;
  for (int k = 0; k < 9; k++) { float dd = v[k] - m; q += dd * dd; }
  float r = rsqrtf(q * (1.0f / 9.0f) + 1e-5f);
  float gg = g[c], bo = bb[c];
  for (int k = 0; k < 9; k++) d[k] = f2bf(gelu_(gg * (v[k] - m) * r + bo));
}

// ---------------- shared GEMM: tile 256x128, BK=64, 8 waves -------------------
// MODE 0: c1   A=W1b(256x512)  B=T  plain          out = HL + bias
// MODE 1: conv A=W2t(5x256x256) B=AL shift+mask    out = HL + bias
// MODE 2: c3   A=W3b(512x256)  B=AL plain          out = X + bias + residual
template <int MODE>
__global__ __launch_bounds__(512) void k_gemm(
    const unsigned short* __restrict__ Aw, const unsigned short* __restrict__ Bsrc,
    const float* __restrict__ bias, unsigned short* __restrict__ Out,
    int Ktot, int nkc) {
  __shared__ unsigned short lA[256 * 64];   // [m][k], 128B rows, XOR-swizzled
  __shared__ unsigned short lB[128 * 64];   // [col][k] transposed, swizzled
  int tid = threadIdx.x;
  int wid = tid >> 6, lane = tid & 63;
  int wm = wid >> 1, wn = wid & 1;
  int m0 = blockIdx.y * 256;
  int col0 = blockIdx.x * 128;
  const int KROW = (MODE == 0) ? 512 : 256;

  f32x4 acc[4][4];
  for (int i = 0; i < 4; i++)
    for (int j = 0; j < 4; j++) acc[i][j] = (f32x4){0.f, 0.f, 0.f, 0.f};

  int ksteps = (MODE == 1) ? 20 : (Ktot / 64);
  for (int ks = 0; ks < ksteps; ks++) {
    int tshift = (MODE == 1) ? (ks >> 2) : 0;
    int kb = (MODE == 1) ? ((ks & 3) * 64) : (ks * 64);

    // ---- stage A (weights) [256 m][64 k], XOR-swizzled
    {
      const unsigned short* Abase = (MODE == 1) ? (Aw + tshift * 65536) : Aw;
      for (int i = 0; i < 4; i++) {
        int gidx = tid + i * 512;             // 0..2047
        int m = gidx >> 3, u = gidx & 7;
        bfv8 av = *(const bfv8*)(Abase + (size_t)(m0 + m) * KROW + kb + u * 8);
        int du = u ^ (m & 7);
        *(bfv8*)(&lA[m * 64 + du * 8]) = av;
      }
    }
    // ---- stage B transposed [128 col][64 k], XOR-swizzled
    for (int s = 0; s < 2; s++) {
      int gidx = tid + s * 512;               // 0..1023
      int krow = gidx & 63;
      int nch = gidx >> 6;                    // 0..15
      int cg = kb + krow;
      int colbase = col0 + nch * 8;
      unsigned short outv[8];
      if (MODE == 1) {
        for (int j = 0; j < 8; j++) {
          int col = colbase + j;
          int n = div9(col);
          int k = col - n * 9;
          int k2 = k + tshift - 2;
          outv[j] = ((unsigned)k2 < 9u)
                        ? Bsrc[(size_t)cg * nkc + col + tshift - 2]
                        : (unsigned short)0;
        }
      } else {
        bfv8 raw = *(const bfv8*)(Bsrc + (size_t)cg * nkc + colbase);
        for (int j = 0; j < 8; j++) outv[j] = (unsigned short)raw[j];
      }
      for (int j = 0; j < 8; j++) {
        int nl = nch * 8 + j;                 // local col 0..127
        int el = krow ^ ((nl & 7) << 3);      // swizzled element index
        lB[nl * 64 + el] = outv[j];
      }
    }
    __syncthreads();

    // ---- MFMA 16x16x32, 2 k-substeps
    int l16 = lane & 15, loct = lane >> 4;
    for (int kk = 0; kk < 2; kk++) {
      bfv8 af[4], bff[4];
      int kbyte = kk * 64 + loct * 16;
      for (int mi = 0; mi < 4; mi++) {
        int row = wm * 64 + mi * 16 + l16;
        int byt = kbyte ^ ((row & 7) << 4);
        af[mi] = *(const bfv8*)((const char*)lA + row * 128 + byt);
      }
      for (int ni = 0; ni < 4; ni++) {
        int row = wn * 64 + ni * 16 + l16;
        int byt = kbyte ^ ((row & 7) << 4);
        bff[ni] = *(const bfv8*)((const char*)lB + row * 128 + byt);
      }
      for (int mi = 0; mi < 4; mi++)
        for (int ni = 0; ni < 4; ni++)
          acc[mi][ni] = __builtin_amdgcn_mfma_f32_16x16x32_bf16(
              af[mi], bff[ni], acc[mi][ni], 0, 0, 0);
    }
    __syncthreads();
  }

  // ---- epilogue: bias (+ residual for MODE 2), bf16 store
  int l16 = lane & 15, lq = lane >> 4;
  for (int mi = 0; mi < 4; mi++) {
    for (int ni = 0; ni < 4; ni++) {
      for (int q = 0; q < 4; q++) {
        int o = m0 + wm * 64 + mi * 16 + lq * 4 + q;
        int col = col0 + wn * 64 + ni * 16 + l16;
        float v = acc[mi][ni][q] + bias[o];
        size_t off = (size_t)o * nkc + col;
        if (MODE == 2) v += bf2f(Out[off]);
        Out[off] = f2bf(v);
      }
    }
  }
}

// ---------------- output projection (fp32 weights) ----------------------------
__global__ void k_out(const unsigned short* X, const float* outw,
                      const float* outb, float* pred,
                      int n0, int ncMask, int nkc) {
  int idx = blockIdx.x * 256 + threadIdx.x;   // nc*8 threads
  int nl = idx >> 3, r = idx & 7;
  if (r >= 7) return;
  int gn = n0 + nl;
  int b = gn >> 11, w = gn & 2047;
  if (w >= 2040) return;
  const float* wr = outw + r * 4608;
  float acc = 0.f;
  for (int c = 0; c < 512; c++) {
    const unsigned short* xp = X + (size_t)c * nkc + nl * 9;
    const float* wp = wr + c * 9;
    #pragma unroll
    for (int k = 0; k < 9; k++) acc += bf2f(xp[k]) * wp[k];
  }
  pred[(b * 2040 + w) * 7 + r] = acc + outb[r];
}

extern "C" void kernel_launch(void* const* d_in, const int* in_sizes, int n_in,
                              void* d_out, int out_size, void* d_ws, size_t ws_size,
                              hipStream_t stream) {
  const int*   x    = (const int*)d_in[0];
  const float* emb  = (const float*)d_in[1];
  const float* ln1w = (const float*)d_in[2];
  const float* ln1b = (const float*)d_in[3];
  const float* ln2w = (const float*)d_in[4];
  const float* ln2b = (const float*)d_in[5];
  const float* ln3w = (const float*)d_in[6];
  const float* ln3b = (const float*)d_in[7];
  const float* c1w  = (const float*)d_in[8];
  const float* c1b  = (const float*)d_in[9];
  const float* c2w  = (const float*)d_in[10];
  const float* c2b  = (const float*)d_in[11];
  const float* c3w  = (const float*)d_in[12];
  const float* c3b  = (const float*)d_in[13];
  const float* outw = (const float*)d_in[14];
  const float* outb = (const float*)d_in[15];
  float* pred = (float*)d_out;

  // ---- adaptive chunk size from actual ws_size -------------------------------
  // footprint(nc) = weights 2359296 B + nc * 9*2*(512 + 512 + 256 + 256) B
  int nc = 16384;
  while (nc > 128 && 2359296ull + (unsigned long long)nc * 27648ull > ws_size)
    nc >>= 1;
  int ncBits = 31 - __builtin_clz(nc);
  int ncMask = nc - 1;
  int nkc = nc * 9;
  int tiles = nkc >> 7;               // nkc / 128 (nc multiple of 128)
  int nchunks = 16384 / nc;

  char* ws = (char*)d_ws;
  unsigned short* W1b = (unsigned short*)(ws);
  unsigned short* W2t = (unsigned short*)(ws + 524288);
  unsigned short* W3b = (unsigned short*)(ws + 1835008);
  char* act = ws + 2359296;
  size_t hiB = (size_t)nc * 9216;     // 512 x nkc bf16
  size_t loB = (size_t)nc * 4608;     // 256 x nkc bf16
  unsigned short* X  = (unsigned short*)(act);
  unsigned short* T  = (unsigned short*)(act + hiB);
  unsigned short* HL = (unsigned short*)(act + 2 * hiB);
  unsigned short* AL = (unsigned short*)(act + 2 * hiB + loB);

  k_prep<<<(1179648 + 255) / 256, 256, 0, stream>>>(c1w, c2w, c3w, W1b, W2t, W3b);

  for (int ch = 0; ch < nchunks; ch++) {
    int n0 = ch * nc;
    k_x0<<<nc * 2, 256, 0, stream>>>(x, emb, X, n0, ncBits, ncMask, nkc);
    for (int l = 0; l < 2; l++) {
      k_ng<<<nc * 2, 256, 0, stream>>>(X, ln1w + l * 512, ln1b + l * 512, T,
                                       ncBits, ncMask, nkc);
      k_gemm<0><<<dim3(tiles, 1), 512, 0, stream>>>(
          W1b + l * 131072, T, c1b + l * 256, HL, 512, nkc);
      k_ng<<<nc, 256, 0, stream>>>(HL, ln2w + l * 256, ln2b + l * 256, AL,
                                   ncBits, ncMask, nkc);
      k_gemm<1><<<dim3(tiles, 1), 512, 0, stream>>>(
          W2t + l * 327680, AL, c2b + l * 256, HL, 256, nkc);
      k_ng<<<nc, 256, 0, stream>>>(HL, ln3w + l * 256, ln3b + l * 256, AL,
                                   ncBits, ncMask, nkc);
      k_gemm<2><<<dim3(tiles, 2), 512, 0, stream>>>(
          W3b + l * 131072, AL, c3b + l * 512, X, 256, nkc);
    }
    k_out<<<nc / 32, 256, 0, stream>>>(X, outw, outb, pred, n0, ncMask, nkc);
  }
}

// Round 3
// 1315.105 us; speedup vs baseline: 1.9130x; 1.9130x over previous
//
#include <hip/hip_runtime.h>

typedef __attribute__((ext_vector_type(8))) short bfv8;
typedef __attribute__((ext_vector_type(4))) float f32x4;
typedef __attribute__((ext_vector_type(4))) unsigned short usv4;

typedef __attribute__((address_space(1))) const void gvoid;
typedef __attribute__((address_space(3))) void lvoid;
__device__ __forceinline__ void gload16(const void* g, void* l) {
  __builtin_amdgcn_global_load_lds((gvoid*)g, (lvoid*)l, 16, 0, 0);
}

__device__ __forceinline__ float bf2f(unsigned short u) {
  union { unsigned int i; float f; } c; c.i = ((unsigned int)u) << 16; return c.f;
}
__device__ __forceinline__ unsigned short f2bf(float f) {
  union { float f; unsigned int i; } c; c.f = f;
  unsigned int r = c.i + 0x7FFFu + ((c.i >> 16) & 1u);
  return (unsigned short)(r >> 16);
}
__device__ __forceinline__ float gelu_(float x) {
  return 0.5f * x * (1.0f + erff(x * 0.70710678118654752f));
}
__device__ __forceinline__ int div9(int col) {
  return (int)(__umulhi((unsigned)col, 954437177u) >> 1);
}

// ---- weight prep: bf16 weights + conv transpose + fp32 out-weight transpose --
__global__ void k_prep(const float* c1w, const float* c2w, const float* c3w,
                       const float* outw, unsigned short* W1b, unsigned short* W2t,
                       unsigned short* W3b, float* OWt) {
  int i = blockIdx.x * 256 + threadIdx.x;
  if (i < 262144) { W1b[i] = f2bf(c1w[i]); return; }
  i -= 262144;
  if (i < 655360) {   // W2t[l][t][o][ii] = c2w[l][o][ii][t]
    int ii = i & 255, o = (i >> 8) & 255, rest = i >> 16;
    int t = rest % 5, l = rest / 5;
    W2t[i] = f2bf(c2w[(((l * 256 + o) << 8) + ii) * 5 + t]);
    return;
  }
  i -= 655360;
  if (i < 262144) { W3b[i] = f2bf(c3w[i]); return; }
  i -= 262144;
  if (i < 32256) {    // OWt[(r*9+k)*512 + c] = outw[r*4608 + c*9 + k]
    int c = i & 511, rk = i >> 9;
    int r = rk / 9, k = rk - 9 * r;
    OWt[i] = outw[r * 4608 + c * 9 + k];
  }
}

// ---- build X0, padded layout [12 + nl*12 + k][512] --------------------------
__global__ void k_x0(const int* x, const float* emb, unsigned short* X, int n0) {
  int idx = blockIdx.x * 256 + threadIdx.x;   // nc*512 threads
  int c = idx & 511, nl = idx >> 9;
  int gn = n0 + nl, b = gn >> 11, w = gn & 2047;
  unsigned short* dst = X + (size_t)(12 + nl * 12) * 512 + c;
  for (int k = 0; k < 9; k++) {
    int t = w + k; if (t > 2047) t = 2047;    // clamp for padded windows
    dst[k * 512] = f2bf(emb[x[(b << 11) + t] * 512 + c]);
  }
}

// ---- fused instance-norm + affine + gelu; PADW zeroes k=9..11 rows ----------
template <int CBITS, bool PADW>
__global__ void k_ng(const unsigned short* H, const float* g, const float* bb,
                     unsigned short* T) {
  const int C = 1 << CBITS;
  int idx = blockIdx.x * 256 + threadIdx.x;
  int c = idx & (C - 1), nl = idx >> CBITS;
  const unsigned short* p = H + (size_t)(12 + nl * 12) * C + c;
  unsigned short* d = T + (size_t)(12 + nl * 12) * C + c;
  float v[9], s = 0.f;
  for (int k = 0; k < 9; k++) { v[k] = bf2f(p[k * C]); s += v[k]; }
  float m = s * (1.0f / 9.0f), q = 0.f;
  for (int k = 0; k < 9; k++) { float dd = v[k] - m; q += dd * dd; }
  float r = rsqrtf(q * (1.0f / 9.0f) + 1e-5f);
  float gg = g[c], bo = bb[c];
  for (int k = 0; k < 9; k++) d[k * C] = f2bf(gelu_(gg * (v[k] - m) * r + bo));
  if (PADW) { d[9 * C] = 0; d[10 * C] = 0; d[11 * C] = 0; }
}

// ---- zero the leading 12 pad rows of AL (read by conv tap shifts) -----------
__global__ void k_zpad(unsigned short* AL) {
  int i = blockIdx.x * 256 + threadIdx.x;
  if (i < 12 * 256) AL[i] = 0;
}

// ---- GEMM: tile 256x128, BK=64, 8 waves, global_load_lds staging ------------
// MODE 0: c1   A=W1b[256][512]   B=T  (512ch)          out=HL(256)
// MODE 1: conv A=W2t[t][256][256] B=AL (256ch, row+t-2) out=HL(256)
// MODE 2: c3   A=W3b[512][256]   B=AL (256ch)          out=X(512) + residual
template <int MODE>
__global__ __launch_bounds__(512) void k_gemm(
    const unsigned short* __restrict__ Aw, const unsigned short* __restrict__ Bsrc,
    const float* __restrict__ bias, unsigned short* __restrict__ Out, int nkc) {
  __shared__ unsigned short lA[256 * 64];   // [m][64ch], chunk-swizzled
  __shared__ unsigned short lB[128 * 64];   // [col][64ch], chunk-swizzled
  const int KROW = (MODE == 0) ? 512 : 256;   // A channel stride
  const int CB   = (MODE == 0) ? 512 : 256;   // B row stride (channels)
  const int CO   = (MODE == 2) ? 512 : 256;   // output channels
  int tid = threadIdx.x;
  int wv = tid >> 6, ln = tid & 63;
  int wm = wv >> 1, wn = wv & 1;
  int m0 = blockIdx.y * 256;
  int col0 = blockIdx.x * 128;
  int lr = ln >> 3, lu = ln & 7;

  // B staging rows (constant across K-steps)
  int brow[2], bswz[2];
  for (int s = 0; s < 2; s++) {
    int nl = s * 64 + wv * 8 + lr;            // local col
    int col = col0 + nl;
    brow[s] = col + 3 * div9(col) + 12;       // padded row index
    bswz[s] = (lu ^ (nl & 7)) * 8;            // pre-swizzled chunk (elems)
  }
  // A staging row parts
  int arow = wv * 8 + lr;                     // + p*64

  f32x4 acc[4][4];
  for (int i = 0; i < 4; i++)
    for (int j = 0; j < 4; j++) acc[i][j] = (f32x4){0.f, 0.f, 0.f, 0.f};

  int ksteps = (MODE == 1) ? 20 : (KROW / 64);
  for (int ks = 0; ks < ksteps; ks++) {
    int kb, dlt;
    const unsigned short* Ab;
    if (MODE == 1) {
      int t = ks >> 2; kb = (ks & 3) * 64; dlt = t - 2; Ab = Aw + t * 65536;
    } else { kb = ks * 64; dlt = 0; Ab = Aw; }

    #pragma unroll
    for (int p = 0; p < 4; p++) {
      int m = p * 64 + arow;
      gload16(Ab + (size_t)(m0 + m) * KROW + kb + (lu ^ (m & 7)) * 8,
              &lA[(p * 64 + wv * 8) * 64]);
    }
    #pragma unroll
    for (int s = 0; s < 2; s++) {
      gload16(Bsrc + (size_t)(brow[s] + dlt) * CB + kb + bswz[s],
              &lB[(s * 64 + wv * 8) * 64]);
    }
    __syncthreads();

    int l16 = ln & 15, loct = ln >> 4;
    #pragma unroll
    for (int kk = 0; kk < 2; kk++) {
      bfv8 af[4], bff[4];
      int kbyte = kk * 64 + loct * 16;
      #pragma unroll
      for (int mi = 0; mi < 4; mi++) {
        int row = wm * 64 + mi * 16 + l16;
        af[mi] = *(const bfv8*)((const char*)lA + row * 128 + (kbyte ^ ((row & 7) << 4)));
      }
      #pragma unroll
      for (int ni = 0; ni < 4; ni++) {
        int row = wn * 64 + ni * 16 + l16;
        bff[ni] = *(const bfv8*)((const char*)lB + row * 128 + (kbyte ^ ((row & 7) << 4)));
      }
      #pragma unroll
      for (int mi = 0; mi < 4; mi++)
        #pragma unroll
        for (int ni = 0; ni < 4; ni++)
          acc[mi][ni] = __builtin_amdgcn_mfma_f32_16x16x32_bf16(
              af[mi], bff[ni], acc[mi][ni], 0, 0, 0);
    }
    __syncthreads();
  }

  // epilogue: 4 consecutive output channels packed into one 8-B store
  int l16 = ln & 15, lq = ln >> 4;
  #pragma unroll
  for (int ni = 0; ni < 4; ni++) {
    int col = col0 + wn * 64 + ni * 16 + l16;
    size_t rbase = (size_t)(col + 3 * div9(col) + 12) * CO;
    #pragma unroll
    for (int mi = 0; mi < 4; mi++) {
      int o = m0 + wm * 64 + mi * 16 + lq * 4;
      usv4* dst = (usv4*)(Out + rbase + o);
      float v[4];
      #pragma unroll
      for (int q = 0; q < 4; q++) v[q] = acc[mi][ni][q] + bias[o + q];
      if (MODE == 2) {
        usv4 old = *dst;
        #pragma unroll
        for (int q = 0; q < 4; q++) v[q] += bf2f(old[q]);
      }
      usv4 pk;
      #pragma unroll
      for (int q = 0; q < 4; q++) pk[q] = f2bf(v[q]);
      *dst = pk;
    }
  }
}

// ---- output projection: one wave per window, fp32 weights -------------------
__global__ void k_out(const unsigned short* X, const float* OWt, const float* outb,
                      float* pred, int n0, int nc) {
  int gw = (blockIdx.x * 256 + threadIdx.x) >> 6;   // wave id = local window
  int ln = threadIdx.x & 63;
  if (gw >= nc) return;
  int gn = n0 + gw, b = gn >> 11, w = gn & 2047;
  if (w >= 2040) return;
  const unsigned short* xb = X + (size_t)(12 + gw * 12) * 512 + ln * 8;
  float a[7];
  #pragma unroll
  for (int r = 0; r < 7; r++) a[r] = 0.f;
  for (int k = 0; k < 9; k++) {
    bfv8 xv = *(const bfv8*)(xb + k * 512);
    float xf[8];
    #pragma unroll
    for (int j = 0; j < 8; j++) xf[j] = bf2f((unsigned short)xv[j]);
    #pragma unroll
    for (int r = 0; r < 7; r++) {
      const float* wp = OWt + (r * 9 + k) * 512 + ln * 8;
      float4 w0 = *(const float4*)(wp);
      float4 w1 = *(const float4*)(wp + 4);
      a[r] += xf[0] * w0.x + xf[1] * w0.y + xf[2] * w0.z + xf[3] * w0.w +
              xf[4] * w1.x + xf[5] * w1.y + xf[6] * w1.z + xf[7] * w1.w;
    }
  }
  #pragma unroll
  for (int r = 0; r < 7; r++)
    for (int off = 32; off; off >>= 1) a[r] += __shfl_down(a[r], off);
  if (ln == 0) {
    float* o = pred + (size_t)(b * 2040 + w) * 7;
    #pragma unroll
    for (int r = 0; r < 7; r++) o[r] = a[r] + outb[r];
  }
}

extern "C" void kernel_launch(void* const* d_in, const int* in_sizes, int n_in,
                              void* d_out, int out_size, void* d_ws, size_t ws_size,
                              hipStream_t stream) {
  const int*   x    = (const int*)d_in[0];
  const float* emb  = (const float*)d_in[1];
  const float* ln1w = (const float*)d_in[2];
  const float* ln1b = (const float*)d_in[3];
  const float* ln2w = (const float*)d_in[4];
  const float* ln2b = (const float*)d_in[5];
  const float* ln3w = (const float*)d_in[6];
  const float* ln3b = (const float*)d_in[7];
  const float* c1w  = (const float*)d_in[8];
  const float* c1b  = (const float*)d_in[9];
  const float* c2w  = (const float*)d_in[10];
  const float* c2b  = (const float*)d_in[11];
  const float* c3w  = (const float*)d_in[12];
  const float* c3b  = (const float*)d_in[13];
  const float* outw = (const float*)d_in[14];
  const float* outb = (const float*)d_in[15];
  float* pred = (float*)d_out;

  // footprint(nc) = weights 2359296 + OWt 129024 + (nc+1)*12*2*(512+512+256+256)
  int nc = 16384;
  while (nc > 128 &&
         2488320ull + (unsigned long long)(nc + 1) * 36864ull > ws_size)
    nc >>= 1;
  int nkc = nc * 9;
  int tiles = nkc >> 7;
  int nchunks = 16384 / nc;

  char* ws = (char*)d_ws;
  unsigned short* W1b = (unsigned short*)(ws);
  unsigned short* W2t = (unsigned short*)(ws + 524288);
  unsigned short* W3b = (unsigned short*)(ws + 1835008);
  float*          OWt = (float*)(ws + 2359296);
  char* act = ws + 2488320;
  size_t hiB = (size_t)(nc + 1) * 12288;     // rows*512*2
  size_t loB = (size_t)(nc + 1) * 6144;      // rows*256*2
  unsigned short* X  = (unsigned short*)(act);
  unsigned short* T  = (unsigned short*)(act + hiB);
  unsigned short* HL = (unsigned short*)(act + 2 * hiB);
  unsigned short* AL = (unsigned short*)(act + 2 * hiB + loB);

  k_prep<<<(1211904 + 255) / 256, 256, 0, stream>>>(c1w, c2w, c3w, outw,
                                                    W1b, W2t, W3b, OWt);

  for (int ch = 0; ch < nchunks; ch++) {
    int n0 = ch * nc;
    k_x0<<<nc * 2, 256, 0, stream>>>(x, emb, X, n0);
    k_zpad<<<12, 256, 0, stream>>>(AL);
    for (int l = 0; l < 2; l++) {
      k_ng<9, false><<<nc * 2, 256, 0, stream>>>(X, ln1w + l * 512,
                                                 ln1b + l * 512, T);
      k_gemm<0><<<dim3(tiles, 1), 512, 0, stream>>>(W1b + l * 131072, T,
                                                    c1b + l * 256, HL, nkc);
      k_ng<8, true><<<nc, 256, 0, stream>>>(HL, ln2w + l * 256,
                                            ln2b + l * 256, AL);
      k_gemm<1><<<dim3(tiles, 1), 512, 0, stream>>>(W2t + l * 327680, AL,
                                                    c2b + l * 256, HL, nkc);
      k_ng<8, true><<<nc, 256, 0, stream>>>(HL, ln3w + l * 256,
                                            ln3b + l * 256, AL);
      k_gemm<2><<<dim3(tiles, 2), 512, 0, stream>>>(W3b + l * 131072, AL,
                                                    c3b + l * 512, X, nkc);
    }
    k_out<<<nc / 4, 256, 0, stream>>>(X, OWt, outb, pred, n0, nc);
  }
}

// Round 4
// 1097.506 us; speedup vs baseline: 2.2923x; 1.1983x over previous
//
#include <hip/hip_runtime.h>

typedef __attribute__((ext_vector_type(8))) short bfv8;
typedef __attribute__((ext_vector_type(4))) float f32x4;

typedef __attribute__((address_space(1))) const void gvoid;
typedef __attribute__((address_space(3))) void lvoid;
__device__ __forceinline__ void gload16(const void* g, void* l) {
  __builtin_amdgcn_global_load_lds((gvoid*)g, (lvoid*)l, 16, 0, 0);
}

__device__ __forceinline__ float bf2f(unsigned short u) {
  union { unsigned int i; float f; } c; c.i = ((unsigned int)u) << 16; return c.f;
}
__device__ __forceinline__ unsigned short f2bf(float f) {
  union { float f; unsigned int i; } c; c.f = f;
  unsigned int r = c.i + 0x7FFFu + ((c.i >> 16) & 1u);
  return (unsigned short)(r >> 16);
}
__device__ __forceinline__ float gelu_(float x) {
  return 0.5f * x * (1.0f + erff(x * 0.70710678118654752f));
}
__device__ __forceinline__ int div9(int col) {
  return (int)(__umulhi((unsigned)col, 954437177u) >> 1);
}

#define SE 146   // epilogue LDS row stride (u16) — 146 => conflict-free re-read

// ---- weight prep: bf16 weights + conv transpose + fp32 out-weight transpose --
__global__ void k_prep(const float* c1w, const float* c2w, const float* c3w,
                       const float* outw, unsigned short* W1b, unsigned short* W2t,
                       unsigned short* W3b, float* OWt) {
  int i = blockIdx.x * 256 + threadIdx.x;
  if (i < 262144) { W1b[i] = f2bf(c1w[i]); return; }
  i -= 262144;
  if (i < 655360) {   // W2t[l][t][o][ii] = c2w[l][o][ii][t]
    int ii = i & 255, o = (i >> 8) & 255, rest = i >> 16;
    int t = rest % 5, l = rest / 5;
    W2t[i] = f2bf(c2w[(((l * 256 + o) << 8) + ii) * 5 + t]);
    return;
  }
  i -= 655360;
  if (i < 262144) { W3b[i] = f2bf(c3w[i]); return; }
  i -= 262144;
  if (i < 32256) {    // OWt[(r*9+k)*512 + c] = outw[r*4608 + c*9 + k]
    int c = i & 511, rk = i >> 9;
    int r = rk / 9, k = rk - 9 * r;
    OWt[i] = outw[r * 4608 + c * 9 + k];
  }
}

// ---- fused: build X0 (bf16) AND T = gelu(inorm1(X0)) from f32 emb -----------
__global__ void k_xng(const int* x, const float* emb, const float* g,
                      const float* bb, unsigned short* X, unsigned short* T,
                      int n0) {
  int idx = blockIdx.x * 256 + threadIdx.x;   // nc*512 threads
  int c = idx & 511, nl = idx >> 9;
  int gn = n0 + nl, b = gn >> 11, w = gn & 2047;
  size_t rbase = (size_t)(12 + nl * 12) * 512 + c;
  float v[9], s = 0.f;
  for (int k = 0; k < 9; k++) {
    int t = w + k; if (t > 2047) t = 2047;    // clamp for padded windows
    v[k] = emb[x[(b << 11) + t] * 512 + c];
    X[rbase + k * 512] = f2bf(v[k]);
    s += v[k];
  }
  float m = s * (1.0f / 9.0f), q = 0.f;
  for (int k = 0; k < 9; k++) { float d = v[k] - m; q += d * d; }
  float r = rsqrtf(q * (1.0f / 9.0f) + 1e-5f);
  float gg = g[c], bo = bb[c];
  for (int k = 0; k < 9; k++)
    T[rbase + k * 512] = f2bf(gelu_(gg * (v[k] - m) * r + bo));
}

// ---- zero leading 12 pad rows of AL (read by conv tap shifts) ---------------
__global__ void k_zpad(unsigned short* AL) {
  int i = threadIdx.x;
  for (; i < 12 * 256; i += 256) AL[i] = 0;
}

// ---- GEMM, tile 256(M) x 144(N = 16 windows), BK=64, 8 waves ----------------
// MODE 0: A=W1b[256][512]   B=T(512ch)            epi: inorm2+gelu -> AL (+pad0)
// MODE 1: A=W2t[5][256][256] B=AL(256ch, shifted) epi: inorm3+gelu -> AL2
// MODE 2: A=W3b[512][256]   B=AL2(256ch)          epi: +bias+resid -> X; WT: inorm1+gelu -> T
template <int MODE, bool WT>
__global__ __launch_bounds__(512) void k_gemm(
    const unsigned short* __restrict__ Aw, const unsigned short* __restrict__ Bsrc,
    const float* __restrict__ cbias, const float* __restrict__ gw,
    const float* __restrict__ gb, unsigned short* __restrict__ Out,
    unsigned short* __restrict__ Tout) {
  __shared__ __align__(16) char smem[51200];
  unsigned short* lA = (unsigned short*)smem;           // [256][64]
  unsigned short* lB = (unsigned short*)(smem + 32768); // [144][64]
  unsigned short* sE = (unsigned short*)smem;           // [128][SE] (epilogue)

  const int KROW = (MODE == 0) ? 512 : 256;   // A row stride == B row stride
  int tid = threadIdx.x, wv = tid >> 6, ln = tid & 63;
  int lr = ln >> 3, lu = ln & 7;
  int m0 = (MODE == 2) ? (blockIdx.y << 8) : 0;
  int w0 = blockIdx.x << 4;
  int col0 = blockIdx.x * 144;

  // B staging source rows / pre-swizzled chunk (constant over K-steps)
  int brow[3], bsw[3];
  #pragma unroll
  for (int s = 0; s < 3; s++) {
    int winst = (s < 2) ? (s * 8 + wv) : (16 + wv);
    int cl = winst * 8 + lr;                  // local col 0..143
    int colg = col0 + cl;
    brow[s] = colg + 3 * div9(colg) + 12;     // padded-layout row
    bsw[s] = (lu ^ (cl & 7)) << 3;
  }
  int arow = (wv << 3) + lr;

  f32x4 acc[2][9];
  #pragma unroll
  for (int i = 0; i < 2; i++)
    #pragma unroll
    for (int j = 0; j < 9; j++) acc[i][j] = (f32x4){0.f, 0.f, 0.f, 0.f};

  int ksteps = (MODE == 1) ? 20 : (KROW >> 6);
  for (int ks = 0; ks < ksteps; ks++) {
    int kb, dlt; const unsigned short* Ab;
    if (MODE == 1) {
      int t = ks >> 2; kb = (ks & 3) << 6; dlt = t - 2; Ab = Aw + t * 65536;
    } else { kb = ks << 6; dlt = 0; Ab = Aw; }

    #pragma unroll
    for (int p = 0; p < 4; p++) {
      int m = (p << 6) + arow;
      gload16(Ab + (size_t)(m0 + m) * KROW + kb + ((lu ^ (m & 7)) << 3),
              lA + ((p << 6) + (wv << 3)) * 64);
    }
    #pragma unroll
    for (int s = 0; s < 2; s++)
      gload16(Bsrc + (size_t)(brow[s] + dlt) * KROW + kb + bsw[s],
              lB + ((s << 3) + wv) * 512);
    if (wv < 2)
      gload16(Bsrc + (size_t)(brow[2] + dlt) * KROW + kb + bsw[2],
              lB + (16 + wv) * 512);
    __syncthreads();

    int l16 = ln & 15, loct = ln >> 4;
    #pragma unroll
    for (int kk = 0; kk < 2; kk++) {
      int kbyte = (kk << 6) + (loct << 4);
      bfv8 af[2], bf_[9];
      #pragma unroll
      for (int mi = 0; mi < 2; mi++) {
        int row = (wv << 5) + (mi << 4) + l16;
        af[mi] = *(const bfv8*)((const char*)lA + row * 128 + (kbyte ^ ((row & 7) << 4)));
      }
      #pragma unroll
      for (int ni = 0; ni < 9; ni++) {
        int row = (ni << 4) + l16;
        bf_[ni] = *(const bfv8*)((const char*)lB + row * 128 + (kbyte ^ ((row & 7) << 4)));
      }
      #pragma unroll
      for (int mi = 0; mi < 2; mi++)
        #pragma unroll
        for (int ni = 0; ni < 9; ni++)
          acc[mi][ni] = __builtin_amdgcn_mfma_f32_16x16x32_bf16(
              af[mi], bf_[ni], acc[mi][ni], 0, 0, 0);
    }
    __syncthreads();
  }

  // ---- fused epilogue: two 128-channel rounds through LDS ------------------
  int l16 = ln & 15, loct = ln >> 4;
  #pragma unroll
  for (int R = 0; R < 2; R++) {
    if ((wv >> 2) == R) {
      #pragma unroll
      for (int mi = 0; mi < 2; mi++)
        #pragma unroll
        for (int ni = 0; ni < 9; ni++)
          #pragma unroll
          for (int q = 0; q < 4; q++) {
            int ch = ((wv & 3) << 5) + (mi << 4) + (loct << 2) + q;  // 0..127
            int col = (ni << 4) + l16;
            sE[ch * SE + col] = f2bf(acc[mi][ni][q]);
          }
    }
    __syncthreads();
    #pragma unroll
    for (int i = 0; i < 4; i++) {
      int task = tid + i * 512;                // 2048 = 128ch x 16win
      int ch2 = task & 127, win = task >> 7;
      int chl = (R << 7) + ch2;
      const unsigned short* se = sE + ch2 * SE + win * 9;
      float v[9];
      #pragma unroll
      for (int k = 0; k < 9; k++) v[k] = bf2f(se[k]);
      size_t ob;
      if (MODE == 2) {
        int chg = m0 + chl;
        float cb = cbias[chg];
        ob = (size_t)(12 + (w0 + win) * 12) * 512 + chg;
        #pragma unroll
        for (int k = 0; k < 9; k++) {
          v[k] += cb + bf2f(Out[ob + k * 512]);   // bias + residual (f32)
          Out[ob + k * 512] = f2bf(v[k]);
        }
      } else {
        ob = (size_t)(12 + (w0 + win) * 12) * 256 + chl;
      }
      if (MODE != 2 || WT) {     // inorm (+affine) + gelu on f32 values
        float s = 0.f;
        #pragma unroll
        for (int k = 0; k < 9; k++) s += v[k];
        float mn = s * (1.0f / 9.0f), qq = 0.f;
        #pragma unroll
        for (int k = 0; k < 9; k++) { float d = v[k] - mn; qq += d * d; }
        float r = rsqrtf(qq * (1.0f / 9.0f) + 1e-5f);
        int gi = (MODE == 2) ? (m0 + chl) : chl;
        float gg = gw[gi], bo = gb[gi];
        if (MODE == 2) {
          #pragma unroll
          for (int k = 0; k < 9; k++)
            Tout[ob + k * 512] = f2bf(gelu_(gg * (v[k] - mn) * r + bo));
        } else {
          #pragma unroll
          for (int k = 0; k < 9; k++)
            Out[ob + k * 256] = f2bf(gelu_(gg * (v[k] - mn) * r + bo));
          if (MODE == 0) {       // zero pad rows (conv tap shifts read them)
            Out[ob + 9 * 256] = 0; Out[ob + 10 * 256] = 0; Out[ob + 11 * 256] = 0;
          }
        }
      }
    }
    __syncthreads();
  }
}

// ---- output projection: one wave per window, fp32 weights -------------------
__global__ void k_out(const unsigned short* X, const float* OWt, const float* outb,
                      float* pred, int n0, int nc) {
  int gw = (blockIdx.x * 256 + threadIdx.x) >> 6;
  int ln = threadIdx.x & 63;
  if (gw >= nc) return;
  int gn = n0 + gw, b = gn >> 11, w = gn & 2047;
  if (w >= 2040) return;
  const unsigned short* xb = X + (size_t)(12 + gw * 12) * 512 + ln * 8;
  float a[7];
  #pragma unroll
  for (int r = 0; r < 7; r++) a[r] = 0.f;
  for (int k = 0; k < 9; k++) {
    bfv8 xv = *(const bfv8*)(xb + k * 512);
    float xf[8];
    #pragma unroll
    for (int j = 0; j < 8; j++) xf[j] = bf2f((unsigned short)xv[j]);
    #pragma unroll
    for (int r = 0; r < 7; r++) {
      const float* wp = OWt + (r * 9 + k) * 512 + ln * 8;
      float4 w0 = *(const float4*)(wp);
      float4 w1 = *(const float4*)(wp + 4);
      a[r] += xf[0] * w0.x + xf[1] * w0.y + xf[2] * w0.z + xf[3] * w0.w +
              xf[4] * w1.x + xf[5] * w1.y + xf[6] * w1.z + xf[7] * w1.w;
    }
  }
  #pragma unroll
  for (int r = 0; r < 7; r++)
    for (int off = 32; off; off >>= 1) a[r] += __shfl_down(a[r], off);
  if (ln == 0) {
    float* o = pred + (size_t)(b * 2040 + w) * 7;
    #pragma unroll
    for (int r = 0; r < 7; r++) o[r] = a[r] + outb[r];
  }
}

extern "C" void kernel_launch(void* const* d_in, const int* in_sizes, int n_in,
                              void* d_out, int out_size, void* d_ws, size_t ws_size,
                              hipStream_t stream) {
  const int*   x    = (const int*)d_in[0];
  const float* emb  = (const float*)d_in[1];
  const float* ln1w = (const float*)d_in[2];
  const float* ln1b = (const float*)d_in[3];
  const float* ln2w = (const float*)d_in[4];
  const float* ln2b = (const float*)d_in[5];
  const float* ln3w = (const float*)d_in[6];
  const float* ln3b = (const float*)d_in[7];
  const float* c1w  = (const float*)d_in[8];
  const float* c2w  = (const float*)d_in[10];
  const float* c3w  = (const float*)d_in[12];
  const float* c3b  = (const float*)d_in[13];
  const float* outw = (const float*)d_in[14];
  const float* outb = (const float*)d_in[15];
  float* pred = (float*)d_out;

  // footprint(nc) = weights 2488320 + (nc+1)*12rows*2B*(512+512+256+256)
  int nc = 16384;
  while (nc > 128 &&
         2488320ull + (unsigned long long)(nc + 1) * 36864ull > ws_size)
    nc >>= 1;
  int tiles = nc >> 4;                 // 144-col tiles = 16 windows each
  int nchunks = 16384 / nc;

  char* ws = (char*)d_ws;
  unsigned short* W1b = (unsigned short*)(ws);
  unsigned short* W2t = (unsigned short*)(ws + 524288);
  unsigned short* W3b = (unsigned short*)(ws + 1835008);
  float*          OWt = (float*)(ws + 2359296);
  char* act = ws + 2488320;
  size_t hiB = (size_t)(nc + 1) * 12288;
  size_t loB = (size_t)(nc + 1) * 6144;
  unsigned short* X   = (unsigned short*)(act);
  unsigned short* T   = (unsigned short*)(act + hiB);
  unsigned short* AL  = (unsigned short*)(act + 2 * hiB);
  unsigned short* AL2 = (unsigned short*)(act + 2 * hiB + loB);

  k_prep<<<(1211904 + 255) / 256, 256, 0, stream>>>(c1w, c2w, c3w, outw,
                                                    W1b, W2t, W3b, OWt);

  for (int ch = 0; ch < nchunks; ch++) {
    int n0 = ch * nc;
    k_zpad<<<1, 256, 0, stream>>>(AL);
    k_xng<<<nc * 2, 256, 0, stream>>>(x, emb, ln1w, ln1b, X, T, n0);
    for (int l = 0; l < 2; l++) {
      k_gemm<0, false><<<dim3(tiles, 1), 512, 0, stream>>>(
          W1b + l * 131072, T, nullptr, ln2w + l * 256, ln2b + l * 256,
          AL, nullptr);
      k_gemm<1, false><<<dim3(tiles, 1), 512, 0, stream>>>(
          W2t + l * 327680, AL, nullptr, ln3w + l * 256, ln3b + l * 256,
          AL2, nullptr);
      if (l == 0)
        k_gemm<2, true><<<dim3(tiles, 2), 512, 0, stream>>>(
            W3b + l * 131072, AL2, c3b + l * 512, ln1w + 512, ln1b + 512,
            X, T);
      else
        k_gemm<2, false><<<dim3(tiles, 2), 512, 0, stream>>>(
            W3b + l * 131072, AL2, c3b + l * 512, nullptr, nullptr,
            X, nullptr);
    }
    k_out<<<nc / 4, 256, 0, stream>>>(X, OWt, outb, pred, n0, nc);
  }
}

// Round 5
// 862.644 us; speedup vs baseline: 2.9164x; 1.2723x over previous
//
#include <hip/hip_runtime.h>

typedef __attribute__((ext_vector_type(8))) short bfv8;
typedef __attribute__((ext_vector_type(4))) float f32x4;
typedef __attribute__((ext_vector_type(4))) unsigned short usv4;

typedef __attribute__((address_space(1))) const void gvoid;
typedef __attribute__((address_space(3))) void lvoid;
__device__ __forceinline__ void gload16(const void* g, void* l) {
  __builtin_amdgcn_global_load_lds((gvoid*)g, (lvoid*)l, 16, 0, 0);
}

__device__ __forceinline__ float bf2f(unsigned short u) {
  union { unsigned int i; float f; } c; c.i = ((unsigned int)u) << 16; return c.f;
}
__device__ __forceinline__ unsigned short f2bf(float f) {
  union { float f; unsigned int i; } c; c.f = f;
  unsigned int r = c.i + 0x7FFFu + ((c.i >> 16) & 1u);
  return (unsigned short)(r >> 16);
}
// tanh-form gelu: x*(1 - 1/(exp(2z)+1)), z = 0.79788456*(x + 0.044715 x^3)
// max |dev| from erf-gelu ~5e-4; hw v_exp + v_rcp, ~9 VALU ops
__device__ __forceinline__ float gelu_(float x) {
  float z2 = 1.5957691216057308f * x * __builtin_fmaf(0.044715f, x * x, 1.0f);
  float e = __expf(z2);
  float t = __builtin_amdgcn_rcpf(e + 1.0f);
  return x - x * t;
}
__device__ __forceinline__ int div9(int col) {
  return (int)(__umulhi((unsigned)col, 954437177u) >> 1);
}

#define CHP 132   // epilogue LDS channel stride (u16), mult of 4 for usv4

// ---- weight prep: bf16 weights + conv transpose + fp32 out-weight transpose --
__global__ void k_prep(const float* c1w, const float* c2w, const float* c3w,
                       const float* outw, unsigned short* W1b, unsigned short* W2t,
                       unsigned short* W3b, float* OWt) {
  int i = blockIdx.x * 256 + threadIdx.x;
  if (i < 262144) { W1b[i] = f2bf(c1w[i]); return; }
  i -= 262144;
  if (i < 655360) {   // W2t[l][t][o][ii] = c2w[l][o][ii][t]
    int ii = i & 255, o = (i >> 8) & 255, rest = i >> 16;
    int t = rest % 5, l = rest / 5;
    W2t[i] = f2bf(c2w[(((l * 256 + o) << 8) + ii) * 5 + t]);
    return;
  }
  i -= 655360;
  if (i < 262144) { W3b[i] = f2bf(c3w[i]); return; }
  i -= 262144;
  if (i < 32256) {    // OWt[(r*9+k)*512 + c] = outw[r*4608 + c*9 + k]
    int c = i & 511, rk = i >> 9;
    int r = rk / 9, k = rk - 9 * r;
    OWt[i] = outw[r * 4608 + c * 9 + k];
  }
}

// ---- fused: build X0 (bf16) AND T = gelu(inorm1(X0)) from f32 emb -----------
__global__ void k_xng(const int* x, const float* emb, const float* g,
                      const float* bb, unsigned short* X, unsigned short* T,
                      int n0) {
  int idx = blockIdx.x * 256 + threadIdx.x;   // nc*512 threads
  int c = idx & 511, nl = idx >> 9;
  int gn = n0 + nl, b = gn >> 11, w = gn & 2047;
  size_t rbase = (size_t)(12 + nl * 12) * 512 + c;
  float v[9], s = 0.f;
  for (int k = 0; k < 9; k++) {
    int t = w + k; if (t > 2047) t = 2047;    // clamp for padded windows
    v[k] = emb[x[(b << 11) + t] * 512 + c];
    X[rbase + k * 512] = f2bf(v[k]);
    s += v[k];
  }
  float m = s * (1.0f / 9.0f), q = 0.f;
  for (int k = 0; k < 9; k++) { float d = v[k] - m; q += d * d; }
  float r = rsqrtf(q * (1.0f / 9.0f) + 1e-5f);
  float gg = g[c], bo = bb[c];
  for (int k = 0; k < 9; k++)
    T[rbase + k * 512] = f2bf(gelu_(gg * (v[k] - m) * r + bo));
}

// ---- zero leading 12 pad rows of AL (read by conv tap shifts) ---------------
__global__ void k_zpad(unsigned short* AL) {
  int i = threadIdx.x;
  for (; i < 12 * 256; i += 256) AL[i] = 0;
}

// ---- GEMM, tile 256(M) x 144(N = 16 windows), BK=64, 8 waves ----------------
// MODE 0: A=W1b[256][512]   B=T(512ch)            epi: inorm2+gelu -> AL (+pad0)
// MODE 1: A=W2t[5][256][256] B=AL(256ch, shifted) epi: inorm3+gelu -> AL2
// MODE 2: A=W3b[512][256]   B=AL2(256ch)          epi: +bias+resid -> X; WT: inorm1+gelu -> T
template <int MODE, bool WT>
__global__ __launch_bounds__(512) void k_gemm(
    const unsigned short* __restrict__ Aw, const unsigned short* __restrict__ Bsrc,
    const float* __restrict__ cbias, const float* __restrict__ gw,
    const float* __restrict__ gb, unsigned short* __restrict__ Out,
    unsigned short* __restrict__ Tout) {
  __shared__ __align__(16) char smem[51200];
  unsigned short* lA = (unsigned short*)smem;           // [256][64]
  unsigned short* lB = (unsigned short*)(smem + 32768); // [144][64]
  unsigned short* sE = (unsigned short*)smem;           // [144 col][CHP ch] epi

  const int KROW = (MODE == 0) ? 512 : 256;   // A row stride == B row stride
  int tid = threadIdx.x, wv = tid >> 6, ln = tid & 63;
  int lr = ln >> 3, lu = ln & 7;
  int m0 = (MODE == 2) ? (blockIdx.y << 8) : 0;
  int w0 = blockIdx.x << 4;
  int col0 = blockIdx.x * 144;

  // B staging source rows / pre-swizzled chunk (constant over K-steps)
  int brow[3], bsw[3];
  #pragma unroll
  for (int s = 0; s < 3; s++) {
    int winst = (s < 2) ? (s * 8 + wv) : (16 + wv);
    int cl = winst * 8 + lr;                  // local col 0..143
    int colg = col0 + cl;
    brow[s] = colg + 3 * div9(colg) + 12;     // padded-layout row
    bsw[s] = (lu ^ (cl & 7)) << 3;
  }
  int arow = (wv << 3) + lr;

  f32x4 acc[2][9];
  #pragma unroll
  for (int i = 0; i < 2; i++)
    #pragma unroll
    for (int j = 0; j < 9; j++) acc[i][j] = (f32x4){0.f, 0.f, 0.f, 0.f};

  int ksteps = (MODE == 1) ? 20 : (KROW >> 6);
  for (int ks = 0; ks < ksteps; ks++) {
    int kb, dlt; const unsigned short* Ab;
    if (MODE == 1) {
      int t = ks >> 2; kb = (ks & 3) << 6; dlt = t - 2; Ab = Aw + t * 65536;
    } else { kb = ks << 6; dlt = 0; Ab = Aw; }

    #pragma unroll
    for (int p = 0; p < 4; p++) {
      int m = (p << 6) + arow;
      gload16(Ab + (size_t)(m0 + m) * KROW + kb + ((lu ^ (m & 7)) << 3),
              lA + ((p << 6) + (wv << 3)) * 64);
    }
    #pragma unroll
    for (int s = 0; s < 2; s++)
      gload16(Bsrc + (size_t)(brow[s] + dlt) * KROW + kb + bsw[s],
              lB + ((s << 3) + wv) * 512);
    if (wv < 2)
      gload16(Bsrc + (size_t)(brow[2] + dlt) * KROW + kb + bsw[2],
              lB + (16 + wv) * 512);
    __syncthreads();

    int l16 = ln & 15, loct = ln >> 4;
    #pragma unroll
    for (int kk = 0; kk < 2; kk++) {
      int kbyte = (kk << 6) + (loct << 4);
      bfv8 af[2], bf_[9];
      #pragma unroll
      for (int mi = 0; mi < 2; mi++) {
        int row = (wv << 5) + (mi << 4) + l16;
        af[mi] = *(const bfv8*)((const char*)lA + row * 128 + (kbyte ^ ((row & 7) << 4)));
      }
      #pragma unroll
      for (int ni = 0; ni < 9; ni++) {
        int row = (ni << 4) + l16;
        bf_[ni] = *(const bfv8*)((const char*)lB + row * 128 + (kbyte ^ ((row & 7) << 4)));
      }
      #pragma unroll
      for (int mi = 0; mi < 2; mi++)
        #pragma unroll
        for (int ni = 0; ni < 9; ni++)
          acc[mi][ni] = __builtin_amdgcn_mfma_f32_16x16x32_bf16(
              af[mi], bf_[ni], acc[mi][ni], 0, 0, 0);
    }
    __syncthreads();
  }

  // ---- fused epilogue: 2 rounds of 128 channels, col-major sE --------------
  int l16 = ln & 15, loct = ln >> 4;
  int c4 = tid & 31, win = tid >> 5;          // reader task: 4-ch group x window
  #pragma unroll
  for (int R = 0; R < 2; R++) {
    if (R) __syncthreads();                   // round-0 reads done
    if ((wv >> 2) == R) {                     // writer waves of this half
      #pragma unroll
      for (int mi = 0; mi < 2; mi++) {
        int chh = ((wv & 3) << 5) + (mi << 4) + (loct << 2);
        #pragma unroll
        for (int ni = 0; ni < 9; ni++) {
          int col = (ni << 4) + l16;
          usv4 pk;
          #pragma unroll
          for (int q = 0; q < 4; q++) pk[q] = f2bf(acc[mi][ni][q]);
          *(usv4*)(sE + col * CHP + chh) = pk;
        }
      }
    }
    __syncthreads();

    int chl = (R << 7) + (c4 << 2);
    const unsigned short* sb = sE + (win * 9) * CHP + (c4 << 2);
    float s1[4] = {0.f, 0.f, 0.f, 0.f}, s2[4] = {0.f, 0.f, 0.f, 0.f};
    float v[9][4];                            // live only for MODE 2
    size_t ob;
    if (MODE == 2) {
      int chg = m0 + chl;
      ob = (size_t)(12 + (w0 + win) * 12) * 512 + chg;
      float cb[4];
      #pragma unroll
      for (int j = 0; j < 4; j++) cb[j] = cbias[chg + j];
      #pragma unroll
      for (int k = 0; k < 9; k++) {
        usv4 rv = *(const usv4*)(sb + k * CHP);
        usv4 old = *(usv4*)(Out + ob + k * 512);
        usv4 pk;
        #pragma unroll
        for (int j = 0; j < 4; j++) {
          float f = bf2f(rv[j]) + cb[j] + bf2f(old[j]);
          v[k][j] = f; s1[j] += f; s2[j] = __builtin_fmaf(f, f, s2[j]);
          pk[j] = f2bf(f);
        }
        *(usv4*)(Out + ob + k * 512) = pk;    // X = resid + bias + conv
      }
    } else {
      ob = (size_t)(12 + (w0 + win) * 12) * 256 + chl;
      #pragma unroll
      for (int k = 0; k < 9; k++) {
        usv4 rv = *(const usv4*)(sb + k * CHP);
        #pragma unroll
        for (int j = 0; j < 4; j++) {
          float f = bf2f(rv[j]);
          s1[j] += f; s2[j] = __builtin_fmaf(f, f, s2[j]);
        }
      }
    }
    if (MODE != 2 || WT) {                    // inorm + affine + gelu
      float mn[4], rr[4], gg[4], bo[4];
      int gi = (MODE == 2) ? (m0 + chl) : chl;
      #pragma unroll
      for (int j = 0; j < 4; j++) {
        mn[j] = s1[j] * (1.0f / 9.0f);
        float var = s2[j] * (1.0f / 9.0f) - mn[j] * mn[j];
        rr[j] = rsqrtf(var + 1e-5f);
        gg[j] = gw[gi + j]; bo[j] = gb[gi + j];
      }
      #pragma unroll
      for (int k = 0; k < 9; k++) {
        usv4 pk;
        if (MODE == 2) {
          #pragma unroll
          for (int j = 0; j < 4; j++)
            pk[j] = f2bf(gelu_(gg[j] * (v[k][j] - mn[j]) * rr[j] + bo[j]));
          *(usv4*)(Tout + ob + k * 512) = pk;
        } else {
          usv4 rv = *(const usv4*)(sb + k * CHP);
          #pragma unroll
          for (int j = 0; j < 4; j++)
            pk[j] = f2bf(gelu_(gg[j] * (bf2f(rv[j]) - mn[j]) * rr[j] + bo[j]));
          *(usv4*)(Out + ob + k * 256) = pk;
        }
      }
      if (MODE == 0) {                        // zero pad rows for conv taps
        usv4 z = (usv4){0, 0, 0, 0};
        *(usv4*)(Out + ob + 9 * 256) = z;
        *(usv4*)(Out + ob + 10 * 256) = z;
        *(usv4*)(Out + ob + 11 * 256) = z;
      }
    }
  }
}

// ---- output projection: one wave per window, fp32 weights -------------------
__global__ void k_out(const unsigned short* X, const float* OWt, const float* outb,
                      float* pred, int n0, int nc) {
  int gw = (blockIdx.x * 256 + threadIdx.x) >> 6;
  int ln = threadIdx.x & 63;
  if (gw >= nc) return;
  int gn = n0 + gw, b = gn >> 11, w = gn & 2047;
  if (w >= 2040) return;
  const unsigned short* xb = X + (size_t)(12 + gw * 12) * 512 + ln * 8;
  float a[7];
  #pragma unroll
  for (int r = 0; r < 7; r++) a[r] = 0.f;
  for (int k = 0; k < 9; k++) {
    bfv8 xv = *(const bfv8*)(xb + k * 512);
    float xf[8];
    #pragma unroll
    for (int j = 0; j < 8; j++) xf[j] = bf2f((unsigned short)xv[j]);
    #pragma unroll
    for (int r = 0; r < 7; r++) {
      const float* wp = OWt + (r * 9 + k) * 512 + ln * 8;
      float4 w0 = *(const float4*)(wp);
      float4 w1 = *(const float4*)(wp + 4);
      a[r] += xf[0] * w0.x + xf[1] * w0.y + xf[2] * w0.z + xf[3] * w0.w +
              xf[4] * w1.x + xf[5] * w1.y + xf[6] * w1.z + xf[7] * w1.w;
    }
  }
  #pragma unroll
  for (int r = 0; r < 7; r++)
    for (int off = 32; off; off >>= 1) a[r] += __shfl_down(a[r], off);
  if (ln == 0) {
    float* o = pred + (size_t)(b * 2040 + w) * 7;
    #pragma unroll
    for (int r = 0; r < 7; r++) o[r] = a[r] + outb[r];
  }
}

extern "C" void kernel_launch(void* const* d_in, const int* in_sizes, int n_in,
                              void* d_out, int out_size, void* d_ws, size_t ws_size,
                              hipStream_t stream) {
  const int*   x    = (const int*)d_in[0];
  const float* emb  = (const float*)d_in[1];
  const float* ln1w = (const float*)d_in[2];
  const float* ln1b = (const float*)d_in[3];
  const float* ln2w = (const float*)d_in[4];
  const float* ln2b = (const float*)d_in[5];
  const float* ln3w = (const float*)d_in[6];
  const float* ln3b = (const float*)d_in[7];
  const float* c1w  = (const float*)d_in[8];
  const float* c2w  = (const float*)d_in[10];
  const float* c3w  = (const float*)d_in[12];
  const float* c3b  = (const float*)d_in[13];
  const float* outw = (const float*)d_in[14];
  const float* outb = (const float*)d_in[15];
  float* pred = (float*)d_out;

  // footprint(nc) = weights 2488320 + (nc+1)*12rows*2B*(512+512+256+256)
  int nc = 16384;
  while (nc > 128 &&
         2488320ull + (unsigned long long)(nc + 1) * 36864ull > ws_size)
    nc >>= 1;
  int tiles = nc >> 4;                 // 144-col tiles = 16 windows each
  int nchunks = 16384 / nc;

  char* ws = (char*)d_ws;
  unsigned short* W1b = (unsigned short*)(ws);
  unsigned short* W2t = (unsigned short*)(ws + 524288);
  unsigned short* W3b = (unsigned short*)(ws + 1835008);
  float*          OWt = (float*)(ws + 2359296);
  char* act = ws + 2488320;
  size_t hiB = (size_t)(nc + 1) * 12288;
  size_t loB = (size_t)(nc + 1) * 6144;
  unsigned short* X   = (unsigned short*)(act);
  unsigned short* T   = (unsigned short*)(act + hiB);
  unsigned short* AL  = (unsigned short*)(act + 2 * hiB);
  unsigned short* AL2 = (unsigned short*)(act + 2 * hiB + loB);

  k_prep<<<(1211904 + 255) / 256, 256, 0, stream>>>(c1w, c2w, c3w, outw,
                                                    W1b, W2t, W3b, OWt);

  for (int ch = 0; ch < nchunks; ch++) {
    int n0 = ch * nc;
    k_zpad<<<1, 256, 0, stream>>>(AL);
    k_xng<<<nc * 2, 256, 0, stream>>>(x, emb, ln1w, ln1b, X, T, n0);
    for (int l = 0; l < 2; l++) {
      k_gemm<0, false><<<dim3(tiles, 1), 512, 0, stream>>>(
          W1b + l * 131072, T, nullptr, ln2w + l * 256, ln2b + l * 256,
          AL, nullptr);
      k_gemm<1, false><<<dim3(tiles, 1), 512, 0, stream>>>(
          W2t + l * 327680, AL, nullptr, ln3w + l * 256, ln3b + l * 256,
          AL2, nullptr);
      if (l == 0)
        k_gemm<2, true><<<dim3(tiles, 2), 512, 0, stream>>>(
            W3b + l * 131072, AL2, c3b + l * 512, ln1w + 512, ln1b + 512,
            X, T);
      else
        k_gemm<2, false><<<dim3(tiles, 2), 512, 0, stream>>>(
            W3b + l * 131072, AL2, c3b + l * 512, nullptr, nullptr,
            X, nullptr);
    }
    k_out<<<nc / 4, 256, 0, stream>>>(X, OWt, outb, pred, n0, nc);
  }
}

// Round 6
// 844.382 us; speedup vs baseline: 2.9795x; 1.0216x over previous
//
#include <hip/hip_runtime.h>

typedef __attribute__((ext_vector_type(8))) short bfv8;
typedef __attribute__((ext_vector_type(4))) float f32x4;
typedef __attribute__((ext_vector_type(4))) unsigned short usv4;

typedef __attribute__((address_space(1))) const void gvoid;
typedef __attribute__((address_space(3))) void lvoid;
__device__ __forceinline__ void gload16(const void* g, void* l) {
  __builtin_amdgcn_global_load_lds((gvoid*)g, (lvoid*)l, 16, 0, 0);
}

__device__ __forceinline__ float bf2f(unsigned short u) {
  union { unsigned int i; float f; } c; c.i = ((unsigned int)u) << 16; return c.f;
}
__device__ __forceinline__ unsigned short f2bf(float f) {
  union { float f; unsigned int i; } c; c.f = f;
  unsigned int r = c.i + 0x7FFFu + ((c.i >> 16) & 1u);
  return (unsigned short)(r >> 16);
}
// tanh-form gelu via hw exp+rcp (max dev from erf-gelu ~5e-4)
__device__ __forceinline__ float gelu_(float x) {
  float z2 = 1.5957691216057308f * x * __builtin_fmaf(0.044715f, x * x, 1.0f);
  float e = __expf(z2);
  float t = __builtin_amdgcn_rcpf(e + 1.0f);
  return x - x * t;
}
__device__ __forceinline__ int div9(int col) {
  return (int)(__umulhi((unsigned)col, 954437177u) >> 1);
}

#define CHP 132   // epilogue LDS channel stride (u16)

// ---- weight prep ------------------------------------------------------------
__global__ void k_prep(const float* c1w, const float* c2w, const float* c3w,
                       const float* outw, unsigned short* W1b, unsigned short* W2t,
                       unsigned short* W3b, float* OWt) {
  int i = blockIdx.x * 256 + threadIdx.x;
  if (i < 262144) { W1b[i] = f2bf(c1w[i]); return; }
  i -= 262144;
  if (i < 655360) {   // W2t[l][t][o][ii] = c2w[l][o][ii][t]
    int ii = i & 255, o = (i >> 8) & 255, rest = i >> 16;
    int t = rest % 5, l = rest / 5;
    W2t[i] = f2bf(c2w[(((l * 256 + o) << 8) + ii) * 5 + t]);
    return;
  }
  i -= 655360;
  if (i < 262144) { W3b[i] = f2bf(c3w[i]); return; }
  i -= 262144;
  if (i < 32256) {    // OWt[(r*9+k)*512 + c] = outw[r*4608 + c*9 + k]
    int c = i & 511, rk = i >> 9;
    int r = rk / 9, k = rk - 9 * r;
    OWt[i] = outw[r * 4608 + c * 9 + k];
  }
}

// ---- build X0, padded layout [12 + nl*12 + k][512] --------------------------
__global__ void k_x0(const int* x, const float* emb, unsigned short* X, int n0) {
  int idx = blockIdx.x * 256 + threadIdx.x;
  int c = idx & 511, nl = idx >> 9;
  int gn = n0 + nl, b = gn >> 11, w = gn & 2047;
  unsigned short* dst = X + (size_t)(12 + nl * 12) * 512 + c;
  for (int k = 0; k < 9; k++) {
    int t = w + k; if (t > 2047) t = 2047;
    dst[k * 512] = f2bf(emb[x[(b << 11) + t] * 512 + c]);
  }
}

// ---- zero leading 12 pad rows of AL (once) -----------------------------------
__global__ void k_zpad(unsigned short* AL) {
  int i = threadIdx.x;
  for (; i < 12 * 256; i += 256) AL[i] = 0;
}

// ---- GEMM, tile 256(M) x 72+8pad(N = 8 windows), BK=64, 8 waves --------------
// MODE 0: A=W1b[256][512]  B=X(512ch) w/ in-LDS inorm1+gelu  epi: inorm2+gelu->AL
// MODE 1: A=W2t[5][256][256] B=AL(256ch, tap-shifted rows)   epi: inorm3+gelu->AL2
// MODE 2: A=W3b[512][256]  B=AL2(256ch)                      epi: +bias+resid->X
template <int MODE>
__global__ __launch_bounds__(512, 4) void k_gemm(
    const unsigned short* __restrict__ Aw, const unsigned short* __restrict__ Bsrc,
    const float* __restrict__ cbias, const float* __restrict__ n1w,
    const float* __restrict__ n1b, const float* __restrict__ gw,
    const float* __restrict__ gb, unsigned short* __restrict__ Out, int nkc) {
  __shared__ __align__(16) char smem[43008];
  unsigned short* lA = (unsigned short*)smem;            // [256][64]
  unsigned short* lB = (unsigned short*)(smem + 32768);  // [80][64]
  unsigned short* sE = (unsigned short*)smem;            // [80][CHP] epilogue

  const int KROW = (MODE == 0) ? 512 : 256;   // A & B row stride (channels)
  int tid = threadIdx.x, wv = tid >> 6, ln = tid & 63;
  int lr = ln >> 3, lu = ln & 7;
  int m0 = (MODE == 2) ? (blockIdx.y << 8) : 0;
  int w0 = blockIdx.x << 3;
  int col0 = blockIdx.x * 72;

  // B staging descriptors (constant over K-steps)
  int cl0 = (wv << 3) + lr;                     // local col 0..63
  int colg0 = col0 + cl0; if (colg0 >= nkc) colg0 = nkc - 1;
  int brow0 = colg0 + 3 * div9(colg0) + 12;
  int bsw0 = (lu ^ (cl0 & 7)) << 3;
  int cl1 = 64 + (wv << 3) + lr;                // local col 64..79 (wv<2)
  int colg1 = col0 + cl1; if (colg1 >= nkc) colg1 = nkc - 1;
  int brow1 = colg1 + 3 * div9(colg1) + 12;
  int bsw1 = (lu ^ (cl1 & 7)) << 3;
  int arow = (wv << 3) + lr;

  f32x4 acc[2][5];
  #pragma unroll
  for (int i = 0; i < 2; i++)
    #pragma unroll
    for (int j = 0; j < 5; j++) acc[i][j] = (f32x4){0.f, 0.f, 0.f, 0.f};

  int ksteps = (MODE == 1) ? 20 : (KROW >> 6);
  for (int ks = 0; ks < ksteps; ks++) {
    int kb, dlt; const unsigned short* Ab;
    if (MODE == 1) {
      int t = ks >> 2; kb = (ks & 3) << 6; dlt = t - 2; Ab = Aw + t * 65536;
    } else { kb = ks << 6; dlt = 0; Ab = Aw; }

    #pragma unroll
    for (int p = 0; p < 4; p++) {
      int m = (p << 6) + arow;
      gload16(Ab + (size_t)(m0 + m) * KROW + kb + ((lu ^ (m & 7)) << 3),
              lA + ((p << 6) + (wv << 3)) * 64);
    }
    gload16(Bsrc + (size_t)(brow0 + dlt) * KROW + kb + bsw0,
            lB + ((wv << 3)) * 64);
    if (wv < 2)
      gload16(Bsrc + (size_t)(brow1 + dlt) * KROW + kb + bsw1,
              lB + ((64 + (wv << 3))) * 64);
    __syncthreads();

    if (MODE == 0) {    // in-LDS inorm1 + gelu on this 64-channel slice
      int gch = kb + ln;
      float gg = n1w[gch], bo = n1b[gch];
      float v[9], s = 0.f;
      #pragma unroll
      for (int k = 0; k < 9; k++) {
        int cl = wv * 9 + k;
        v[k] = bf2f(lB[cl * 64 + (((ln >> 3) ^ (cl & 7)) << 3) + (ln & 7)]);
        s += v[k];
      }
      float mn = s * (1.0f / 9.0f), q = 0.f;
      #pragma unroll
      for (int k = 0; k < 9; k++) { float d = v[k] - mn; q += d * d; }
      float r = rsqrtf(q * (1.0f / 9.0f) + 1e-5f);
      #pragma unroll
      for (int k = 0; k < 9; k++) {
        int cl = wv * 9 + k;
        lB[cl * 64 + (((ln >> 3) ^ (cl & 7)) << 3) + (ln & 7)] =
            f2bf(gelu_(gg * (v[k] - mn) * r + bo));
      }
      __syncthreads();
    }

    int l16 = ln & 15, loct = ln >> 4;
    #pragma unroll
    for (int kk = 0; kk < 2; kk++) {
      int kbyte = (kk << 6) + (loct << 4);
      bfv8 af[2], bf_[5];
      #pragma unroll
      for (int mi = 0; mi < 2; mi++) {
        int row = (wv << 5) + (mi << 4) + l16;
        af[mi] = *(const bfv8*)((const char*)lA + row * 128 + (kbyte ^ ((row & 7) << 4)));
      }
      #pragma unroll
      for (int ni = 0; ni < 5; ni++) {
        int row = (ni << 4) + l16;
        bf_[ni] = *(const bfv8*)((const char*)lB + row * 128 + (kbyte ^ ((row & 7) << 4)));
      }
      #pragma unroll
      for (int mi = 0; mi < 2; mi++)
        #pragma unroll
        for (int ni = 0; ni < 5; ni++)
          acc[mi][ni] = __builtin_amdgcn_mfma_f32_16x16x32_bf16(
              af[mi], bf_[ni], acc[mi][ni], 0, 0, 0);
    }
    __syncthreads();
  }

  // ---- fused epilogue: 2 rounds of 128 channels, col-major sE ----------------
  int l16 = ln & 15, loct = ln >> 4;
  int c4 = tid & 31, win = tid >> 5;            // reader task (tid<256)
  #pragma unroll
  for (int R = 0; R < 2; R++) {
    if (R) __syncthreads();
    if ((wv >> 2) == R) {
      #pragma unroll
      for (int mi = 0; mi < 2; mi++) {
        int chh = ((wv & 3) << 5) + (mi << 4) + (loct << 2);
        #pragma unroll
        for (int ni = 0; ni < 5; ni++) {
          int col = (ni << 4) + l16;
          usv4 pk;
          #pragma unroll
          for (int q = 0; q < 4; q++) pk[q] = f2bf(acc[mi][ni][q]);
          *(usv4*)(sE + col * CHP + chh) = pk;
        }
      }
    }
    __syncthreads();
    if (tid < 256) {
      int chl = (R << 7) + (c4 << 2);
      const unsigned short* sb = sE + (win * 9) * CHP + (c4 << 2);
      if (MODE == 2) {
        int chg = m0 + chl;
        size_t ob = (size_t)(12 + (size_t)(w0 + win) * 12) * 512 + chg;
        float cb[4];
        #pragma unroll
        for (int j = 0; j < 4; j++) cb[j] = cbias[chg + j];
        #pragma unroll
        for (int k = 0; k < 9; k++) {
          usv4 rv = *(const usv4*)(sb + k * CHP);
          usv4 old = *(usv4*)(Out + ob + k * 512);
          usv4 pk;
          #pragma unroll
          for (int j = 0; j < 4; j++)
            pk[j] = f2bf(bf2f(rv[j]) + cb[j] + bf2f(old[j]));
          *(usv4*)(Out + ob + k * 512) = pk;
        }
      } else {
        size_t ob = (size_t)(12 + (size_t)(w0 + win) * 12) * 256 + chl;
        float s1[4] = {0.f, 0.f, 0.f, 0.f}, s2[4] = {0.f, 0.f, 0.f, 0.f};
        #pragma unroll
        for (int k = 0; k < 9; k++) {
          usv4 rv = *(const usv4*)(sb + k * CHP);
          #pragma unroll
          for (int j = 0; j < 4; j++) {
            float f = bf2f(rv[j]);
            s1[j] += f; s2[j] = __builtin_fmaf(f, f, s2[j]);
          }
        }
        float mn[4], rr[4], gg[4], bo[4];
        #pragma unroll
        for (int j = 0; j < 4; j++) {
          mn[j] = s1[j] * (1.0f / 9.0f);
          float var = s2[j] * (1.0f / 9.0f) - mn[j] * mn[j];
          rr[j] = rsqrtf(var + 1e-5f);
          gg[j] = gw[chl + j]; bo[j] = gb[chl + j];
        }
        #pragma unroll
        for (int k = 0; k < 9; k++) {
          usv4 rv = *(const usv4*)(sb + k * CHP);
          usv4 pk;
          #pragma unroll
          for (int j = 0; j < 4; j++)
            pk[j] = f2bf(gelu_(gg[j] * (bf2f(rv[j]) - mn[j]) * rr[j] + bo[j]));
          *(usv4*)(Out + ob + k * 256) = pk;
        }
        if (MODE == 0) {     // zero window pad rows for conv tap shifts
          usv4 z = (usv4){0, 0, 0, 0};
          *(usv4*)(Out + ob + 9 * 256) = z;
          *(usv4*)(Out + ob + 10 * 256) = z;
          *(usv4*)(Out + ob + 11 * 256) = z;
        }
      }
    }
  }
}

// ---- output projection: one wave per window, fp32 weights -------------------
__global__ void k_out(const unsigned short* X, const float* OWt, const float* outb,
                      float* pred, int n0, int nc) {
  int gw = (blockIdx.x * 256 + threadIdx.x) >> 6;
  int ln = threadIdx.x & 63;
  if (gw >= nc) return;
  int gn = n0 + gw, b = gn >> 11, w = gn & 2047;
  if (w >= 2040) return;
  const unsigned short* xb = X + (size_t)(12 + gw * 12) * 512 + ln * 8;
  float a[7];
  #pragma unroll
  for (int r = 0; r < 7; r++) a[r] = 0.f;
  for (int k = 0; k < 9; k++) {
    bfv8 xv = *(const bfv8*)(xb + k * 512);
    float xf[8];
    #pragma unroll
    for (int j = 0; j < 8; j++) xf[j] = bf2f((unsigned short)xv[j]);
    #pragma unroll
    for (int r = 0; r < 7; r++) {
      const float* wp = OWt + (r * 9 + k) * 512 + ln * 8;
      float4 w0 = *(const float4*)(wp);
      float4 w1 = *(const float4*)(wp + 4);
      a[r] += xf[0] * w0.x + xf[1] * w0.y + xf[2] * w0.z + xf[3] * w0.w +
              xf[4] * w1.x + xf[5] * w1.y + xf[6] * w1.z + xf[7] * w1.w;
    }
  }
  #pragma unroll
  for (int r = 0; r < 7; r++)
    for (int off = 32; off; off >>= 1) a[r] += __shfl_down(a[r], off);
  if (ln == 0) {
    float* o = pred + (size_t)(b * 2040 + w) * 7;
    #pragma unroll
    for (int r = 0; r < 7; r++) o[r] = a[r] + outb[r];
  }
}

extern "C" void kernel_launch(void* const* d_in, const int* in_sizes, int n_in,
                              void* d_out, int out_size, void* d_ws, size_t ws_size,
                              hipStream_t stream) {
  const int*   x    = (const int*)d_in[0];
  const float* emb  = (const float*)d_in[1];
  const float* ln1w = (const float*)d_in[2];
  const float* ln1b = (const float*)d_in[3];
  const float* ln2w = (const float*)d_in[4];
  const float* ln2b = (const float*)d_in[5];
  const float* ln3w = (const float*)d_in[6];
  const float* ln3b = (const float*)d_in[7];
  const float* c1w  = (const float*)d_in[8];
  const float* c2w  = (const float*)d_in[10];
  const float* c3w  = (const float*)d_in[12];
  const float* c3b  = (const float*)d_in[13];
  const float* outw = (const float*)d_in[14];
  const float* outb = (const float*)d_in[15];
  float* pred = (float*)d_out;

  // footprint(nc) = weights 2488320 + (nc+1)*12rows*2B*(512+256+256)
  int nc = 16384;
  while (nc > 128 &&
         2488320ull + (unsigned long long)(nc + 1) * 24576ull > ws_size)
    nc >>= 1;
  int nkc = nc * 9;
  int tiles = nc >> 3;                 // 72-col tiles = 8 windows each
  int nchunks = 16384 / nc;

  char* ws = (char*)d_ws;
  unsigned short* W1b = (unsigned short*)(ws);
  unsigned short* W2t = (unsigned short*)(ws + 524288);
  unsigned short* W3b = (unsigned short*)(ws + 1835008);
  float*          OWt = (float*)(ws + 2359296);
  char* act = ws + 2488320;
  size_t hiB = (size_t)(nc + 1) * 12288;
  size_t loB = (size_t)(nc + 1) * 6144;
  unsigned short* X   = (unsigned short*)(act);
  unsigned short* AL  = (unsigned short*)(act + hiB);
  unsigned short* AL2 = (unsigned short*)(act + hiB + loB);

  k_prep<<<(1211904 + 255) / 256, 256, 0, stream>>>(c1w, c2w, c3w, outw,
                                                    W1b, W2t, W3b, OWt);
  k_zpad<<<1, 256, 0, stream>>>(AL);

  for (int ch = 0; ch < nchunks; ch++) {
    int n0 = ch * nc;
    k_x0<<<nc * 2, 256, 0, stream>>>(x, emb, X, n0);
    for (int l = 0; l < 2; l++) {
      k_gemm<0><<<dim3(tiles, 1), 512, 0, stream>>>(
          W1b + l * 131072, X, nullptr, ln1w + l * 512, ln1b + l * 512,
          ln2w + l * 256, ln2b + l * 256, AL, nkc);
      k_gemm<1><<<dim3(tiles, 1), 512, 0, stream>>>(
          W2t + l * 327680, AL, nullptr, nullptr, nullptr,
          ln3w + l * 256, ln3b + l * 256, AL2, nkc);
      k_gemm<2><<<dim3(tiles, 2), 512, 0, stream>>>(
          W3b + l * 131072, AL2, c3b + l * 512, nullptr, nullptr,
          nullptr, nullptr, X, nkc);
    }
    k_out<<<nc / 4, 256, 0, stream>>>(X, OWt, outb, pred, n0, nc);
  }
}